// Round 9
// baseline (335.953 us; speedup 1.0000x reference)
//
#include <hip/hip_runtime.h>

// GCN 2-layer forward. CSR-gather, bf16 payloads at stride-64 (128 B rows),
// 4-edges-per-gather aggregation. Adjacency per node SORTED BY SRC so all
// concurrent waves sweep src-space together -> moving gather window fits
// per-XCD L2. Pipeline: zero -> part -> build -> mm1 -> agg1 -> mm2 -> agg2.

#define FIN 128
#define F1  64
#define F2  41
#define FP  64     // payload row stride (bf16 elems): 128 B, 2 lines, aligned

#define BSH    8                 // bucket = dst >> 8 (256 nodes/bucket)
#define BCAP   6144              // per-bucket edge window (mean 4096, >30 sigma)
#define NBMAX  512               // max buckets (n <= 131072)
#define CHUNK_P 4096             // edges per k_part workgroup (391 wgs)

#define MT 128                   // GEMM M-tile
#define KC 16                    // GEMM K-chunk

__device__ __forceinline__ unsigned short f2bf(float f) {
    unsigned u = __builtin_bit_cast(unsigned, f);
    u += 0x7FFFu + ((u >> 16) & 1u);           // RNE
    return (unsigned short)(u >> 16);
}
__device__ __forceinline__ float bf2f(unsigned short h) {
    unsigned u = ((unsigned)h) << 16;
    return __builtin_bit_cast(float, u);
}

__global__ void k_zero(int* __restrict__ p, int n) {
    int i = blockIdx.x * blockDim.x + threadIdx.x;
    if (i < n) p[i] = 0;
}

// ---- pass 1: chunk-local CSR in LDS, coalesced copy-out to bucket windows --
__global__ __launch_bounds__(256) void k_part(
    const int* __restrict__ src, const int* __restrict__ dst,
    int* __restrict__ gcur, int* __restrict__ pairs, int E) {
    __shared__ int hist[NBMAX];     // count -> local cursor
    __shared__ int gsh[NBMAX];      // absolute pairs-index shift per bucket
    __shared__ int lex[256];
    __shared__ int limg[CHUNK_P];   // 16 KB local packed pairs
    __shared__ int lsh[CHUNK_P];    // 16 KB per-slot shift
    __shared__ int stot;
    int tid = threadIdx.x;
    int e0  = blockIdx.x * CHUNK_P;
    hist[tid] = 0; hist[tid + 256] = 0;
    __syncthreads();
    for (int j = 0; j < CHUNK_P / 256; j++) {
        int e = e0 + j * 256 + tid;
        if (e < E) atomicAdd(&hist[dst[e] >> BSH], 1);
    }
    __syncthreads();
    int b0 = 2 * tid, b1 = 2 * tid + 1;
    int c0 = hist[b0], c1 = hist[b1];
    int s  = c0 + c1;
    lex[tid] = s;
    __syncthreads();
    for (int off = 1; off < 256; off <<= 1) {
        int v = lex[tid];
        int a = (tid >= off) ? lex[tid - off] : 0;
        __syncthreads();
        lex[tid] = v + a;
        __syncthreads();
    }
    int incl = lex[tid];
    if (tid == 255) stot = incl;
    int ex = incl - s;
    int l0 = ex, l1 = ex + c0;
    int g0 = c0 ? atomicAdd(&gcur[b0], c0) : 0;
    int g1 = c1 ? atomicAdd(&gcur[b1], c1) : 0;
    hist[b0] = l0; hist[b1] = l1;
    gsh[b0]  = b0 * BCAP + g0 - l0;
    gsh[b1]  = b1 * BCAP + g1 - l1;
    __syncthreads();
    for (int j = 0; j < CHUNK_P / 256; j++) {
        int e = e0 + j * 256 + tid;
        if (e < E) {
            int d = dst[e], sv = src[e];
            int b = d >> BSH;
            int p = atomicAdd(&hist[b], 1);
            limg[p] = (sv << BSH) | (d & 255);
            lsh[p]  = gsh[b];
        }
    }
    __syncthreads();
    int tot = stot;
    for (int k = tid; k < tot; k += 256)
        pairs[k + lsh[k]] = limg[k];
}

// ---- pass 2: per-bucket CSR build in LDS + per-node src-sort ---------------
__global__ __launch_bounds__(256) void k_build(
    const int* __restrict__ gcur, const int* __restrict__ pairs,
    int* __restrict__ adjcur, int* __restrict__ adj,
    int2* __restrict__ rowinfo, float* __restrict__ dinv, int n) {
    __shared__ int lcnt[256];
    __shared__ int lex[256];
    __shared__ int lcur[256];
    __shared__ int ladj[BCAP];
    __shared__ int sbase;
    int tid = threadIdx.x;
    int b   = blockIdx.x;
    int cntb  = gcur[b]; if (cntb > BCAP) cntb = BCAP;
    int node0 = b << BSH;
    const int* pb = pairs + (size_t)b * BCAP;

    if (tid == 0) sbase = atomicAdd(adjcur, cntb);
    lcnt[tid] = 0;
    __syncthreads();
    for (int k = tid; k < cntb; k += 256) atomicAdd(&lcnt[pb[k] & 255], 1);
    __syncthreads();
    int own = lcnt[tid];
    lex[tid] = own;
    __syncthreads();
    for (int off = 1; off < 256; off <<= 1) {
        int val = lex[tid];
        int add = (tid >= off) ? lex[tid - off] : 0;
        __syncthreads();
        lex[tid] = val + add;
        __syncthreads();
    }
    int excl = lex[tid] - own;
    __syncthreads();
    lex[tid]  = excl;
    lcur[tid] = excl;
    __syncthreads();
    for (int k = tid; k < cntb; k += 256) {
        int pk  = pb[k];
        int pos = atomicAdd(&lcur[pk & 255], 1);
        ladj[pos] = pk >> BSH;
    }
    __syncthreads();
    // per-node insertion sort by src (each thread owns a disjoint segment) --
    // gives all agg waves a monotone sweep through src-space (L2 locality).
    {
        int s0 = excl;
        for (int i = 1; i < own; i++) {
            int key = ladj[s0 + i];
            int j = i - 1;
            while (j >= 0 && ladj[s0 + j] > key) {
                ladj[s0 + j + 1] = ladj[s0 + j];
                j--;
            }
            ladj[s0 + j + 1] = key;
        }
    }
    __syncthreads();
    int base = sbase;
    for (int k = tid; k < cntb; k += 256) adj[base + k] = ladj[k];
    int node = node0 + tid;
    if (node < n) {
        rowinfo[node] = make_int2(base + excl, own);
        dinv[node]    = rsqrtf((float)own + 1.0f);
    }
}

// ---- layer 1 GEMM (tiled): hs1 = bf16( (x @ W1) * dinv ) -------------------
__global__ __launch_bounds__(256) void k_mm1(
    const float* __restrict__ x, const float* __restrict__ W1,
    const float* __restrict__ dinv, unsigned short* __restrict__ hs, int n) {
    __shared__ float Ws[FIN * F1];   // 32 KB
    __shared__ float As[KC][MT];     // 8 KB
    int t  = threadIdx.x;
    int n0 = blockIdx.x * MT;
#pragma unroll
    for (int j = 0; j < 8; j++) {
        int f = j * 256 + t;
        ((float4*)Ws)[f] = ((const float4*)W1)[f];
    }
    int m0 = (t & 15) * 8;
    int c0 = (t >> 4) * 4;
    int m_l = t & 127;
    int kh  = (t >> 7) * 8;
    bool mvalid = (n0 + m_l) < n;
    const float* xrow = x + (size_t)(n0 + m_l) * FIN + kh;
    float acc[8][4] = {};
    for (int kc = 0; kc < FIN; kc += KC) {
        __syncthreads();
        float4 v0 = mvalid ? *(const float4*)(xrow + kc)     : float4{0.f,0.f,0.f,0.f};
        float4 v1 = mvalid ? *(const float4*)(xrow + kc + 4) : float4{0.f,0.f,0.f,0.f};
        As[kh + 0][m_l] = v0.x; As[kh + 1][m_l] = v0.y;
        As[kh + 2][m_l] = v0.z; As[kh + 3][m_l] = v0.w;
        As[kh + 4][m_l] = v1.x; As[kh + 5][m_l] = v1.y;
        As[kh + 6][m_l] = v1.z; As[kh + 7][m_l] = v1.w;
        __syncthreads();
#pragma unroll
        for (int k = 0; k < KC; k++) {
            float4 a0 = *(const float4*)&As[k][m0];
            float4 a1 = *(const float4*)&As[k][m0 + 4];
            float4 w  = *(const float4*)&Ws[(kc + k) * F1 + c0];
            float a[8] = {a0.x, a0.y, a0.z, a0.w, a1.x, a1.y, a1.z, a1.w};
#pragma unroll
            for (int i = 0; i < 8; i++) {
                acc[i][0] += a[i] * w.x;
                acc[i][1] += a[i] * w.y;
                acc[i][2] += a[i] * w.z;
                acc[i][3] += a[i] * w.w;
            }
        }
    }
#pragma unroll
    for (int i = 0; i < 8; i++) {
        int node = n0 + m0 + i;
        if (node < n) {
            float dv = dinv[node];
            ushort4 o = { f2bf(acc[i][0] * dv), f2bf(acc[i][1] * dv),
                          f2bf(acc[i][2] * dv), f2bf(acc[i][3] * dv) };
            *(ushort4*)&hs[((size_t)node << 6) + c0] = o;
        }
    }
}

// ---- layer 1 aggregate: h1 = bf16(relu(dinv*(gather+self) + b1)) -----------
__global__ __launch_bounds__(256) void k_agg1(
    const int2* __restrict__ rowinfo, const int* __restrict__ adj,
    const unsigned short* __restrict__ hs, const float* __restrict__ dinv,
    const float* __restrict__ b1, unsigned short* __restrict__ h1b, int n, int E) {
    int node = blockIdx.x * 4 + (threadIdx.x >> 6);
    if (node >= n) return;
    int lane = threadIdx.x & 63;
    int grp  = lane >> 4;
    int p4   = (lane & 15) * 4;      // feature quad base
    int2 ri = rowinfo[node];
    int beg = ri.x, deg = ri.y;
    float4 acc = {0.f, 0.f, 0.f, 0.f};
    if (grp == 0) {                  // self-loop (counted once)
        ushort4 u = *(const ushort4*)&hs[((size_t)node << 6) + p4];
        acc.x = bf2f(u.x); acc.y = bf2f(u.y); acc.z = bf2f(u.z); acc.w = bf2f(u.w);
    }
    for (int base = 0; base < deg; base += 64) {
        int m = deg - base; if (m > 64) m = 64;
        int idx = beg + base + lane;
        int myoff = adj[idx < E ? idx : 0] << 6;   // element offset (stride 64)
        int e = 0;
        for (; e + 16 <= m; e += 16) {
            int o0 = __shfl(myoff, e + grp),      o1 = __shfl(myoff, e + 4 + grp);
            int o2 = __shfl(myoff, e + 8 + grp),  o3 = __shfl(myoff, e + 12 + grp);
            ushort4 u0 = *(const ushort4*)&hs[(size_t)o0 + p4];
            ushort4 u1 = *(const ushort4*)&hs[(size_t)o1 + p4];
            ushort4 u2 = *(const ushort4*)&hs[(size_t)o2 + p4];
            ushort4 u3 = *(const ushort4*)&hs[(size_t)o3 + p4];
            acc.x += (bf2f(u0.x) + bf2f(u1.x)) + (bf2f(u2.x) + bf2f(u3.x));
            acc.y += (bf2f(u0.y) + bf2f(u1.y)) + (bf2f(u2.y) + bf2f(u3.y));
            acc.z += (bf2f(u0.z) + bf2f(u1.z)) + (bf2f(u2.z) + bf2f(u3.z));
            acc.w += (bf2f(u0.w) + bf2f(u1.w)) + (bf2f(u2.w) + bf2f(u3.w));
        }
        for (; e < m; e += 4) {
            int sl = e + grp;
            int o = __shfl(myoff, sl);
            if (sl < m) {
                ushort4 u = *(const ushort4*)&hs[(size_t)o + p4];
                acc.x += bf2f(u.x); acc.y += bf2f(u.y);
                acc.z += bf2f(u.z); acc.w += bf2f(u.w);
            }
        }
    }
    acc.x += __shfl_xor(acc.x, 16); acc.y += __shfl_xor(acc.y, 16);
    acc.z += __shfl_xor(acc.z, 16); acc.w += __shfl_xor(acc.w, 16);
    acc.x += __shfl_xor(acc.x, 32); acc.y += __shfl_xor(acc.y, 32);
    acc.z += __shfl_xor(acc.z, 32); acc.w += __shfl_xor(acc.w, 32);
    if (grp == 0) {
        float dv = dinv[node];
        float4 bg = *(const float4*)&b1[p4];
        float vx = acc.x * dv + bg.x; vx = vx > 0.f ? vx : 0.f;
        float vy = acc.y * dv + bg.y; vy = vy > 0.f ? vy : 0.f;
        float vz = acc.z * dv + bg.z; vz = vz > 0.f ? vz : 0.f;
        float vw = acc.w * dv + bg.w; vw = vw > 0.f ? vw : 0.f;
        ushort4 o = { f2bf(vx), f2bf(vy), f2bf(vz), f2bf(vw) };
        *(ushort4*)&h1b[((size_t)node << 6) + p4] = o;
    }
}

// ---- layer 2 GEMM (tiled): hs2 = bf16( (h1 @ W2) * dinv ), stride 64 -------
// h1 input is bf16 (converted during staging). W2 zero-padded to 64 cols.
__global__ __launch_bounds__(256) void k_mm2(
    const unsigned short* __restrict__ h1b, const float* __restrict__ W2,
    const float* __restrict__ dinv, unsigned short* __restrict__ hs2, int n) {
    __shared__ float Ws[F1 * FP];    // 16 KB padded
    __shared__ float As[KC][MT];
    int t  = threadIdx.x;
    int n0 = blockIdx.x * MT;
    for (int idx = t; idx < F1 * FP; idx += 256) {
        int k = idx >> 6, c = idx & 63;
        Ws[idx] = (c < F2) ? W2[k * F2 + c] : 0.f;
    }
    int m0 = (t & 15) * 8;
    int c0 = (t >> 4) * 4;
    int m_l = t & 127;
    int kh  = (t >> 7) * 8;
    bool mvalid = (n0 + m_l) < n;
    const unsigned short* hrow = h1b + ((size_t)(n0 + m_l) << 6) + kh;
    float acc[8][4] = {};
    for (int kc = 0; kc < F1; kc += KC) {
        __syncthreads();
        ushort4 u0 = mvalid ? *(const ushort4*)(hrow + kc)     : ushort4{0,0,0,0};
        ushort4 u1 = mvalid ? *(const ushort4*)(hrow + kc + 4) : ushort4{0,0,0,0};
        As[kh + 0][m_l] = bf2f(u0.x); As[kh + 1][m_l] = bf2f(u0.y);
        As[kh + 2][m_l] = bf2f(u0.z); As[kh + 3][m_l] = bf2f(u0.w);
        As[kh + 4][m_l] = bf2f(u1.x); As[kh + 5][m_l] = bf2f(u1.y);
        As[kh + 6][m_l] = bf2f(u1.z); As[kh + 7][m_l] = bf2f(u1.w);
        __syncthreads();
#pragma unroll
        for (int k = 0; k < KC; k++) {
            float4 a0 = *(const float4*)&As[k][m0];
            float4 a1 = *(const float4*)&As[k][m0 + 4];
            float4 w  = *(const float4*)&Ws[(kc + k) * FP + c0];
            float a[8] = {a0.x, a0.y, a0.z, a0.w, a1.x, a1.y, a1.z, a1.w};
#pragma unroll
            for (int i = 0; i < 8; i++) {
                acc[i][0] += a[i] * w.x;
                acc[i][1] += a[i] * w.y;
                acc[i][2] += a[i] * w.z;
                acc[i][3] += a[i] * w.w;
            }
        }
    }
#pragma unroll
    for (int i = 0; i < 8; i++) {
        int node = n0 + m0 + i;
        if (node < n) {
            float dv = dinv[node];
            ushort4 o = { f2bf(acc[i][0] * dv), f2bf(acc[i][1] * dv),
                          f2bf(acc[i][2] * dv), f2bf(acc[i][3] * dv) };
            *(ushort4*)&hs2[((size_t)node << 6) + c0] = o;
        }
    }
}

// ---- layer 2 aggregate: out = dinv*(gather+self) + b2 ----------------------
__global__ __launch_bounds__(256) void k_agg2(
    const int2* __restrict__ rowinfo, const int* __restrict__ adj,
    const unsigned short* __restrict__ hs2, const float* __restrict__ dinv,
    const float* __restrict__ b2, float* __restrict__ out, int n, int E) {
    int node = blockIdx.x * 4 + (threadIdx.x >> 6);
    if (node >= n) return;
    int lane = threadIdx.x & 63;
    int grp  = lane >> 4;
    int p4   = (lane & 15) * 4;
    int2 ri = rowinfo[node];
    int beg = ri.x, deg = ri.y;
    float4 acc = {0.f, 0.f, 0.f, 0.f};
    if (grp == 0) {
        ushort4 u = *(const ushort4*)&hs2[((size_t)node << 6) + p4];
        acc.x = bf2f(u.x); acc.y = bf2f(u.y); acc.z = bf2f(u.z); acc.w = bf2f(u.w);
    }
    for (int base = 0; base < deg; base += 64) {
        int m = deg - base; if (m > 64) m = 64;
        int idx = beg + base + lane;
        int myoff = adj[idx < E ? idx : 0] << 6;
        int e = 0;
        for (; e + 16 <= m; e += 16) {
            int o0 = __shfl(myoff, e + grp),      o1 = __shfl(myoff, e + 4 + grp);
            int o2 = __shfl(myoff, e + 8 + grp),  o3 = __shfl(myoff, e + 12 + grp);
            ushort4 u0 = *(const ushort4*)&hs2[(size_t)o0 + p4];
            ushort4 u1 = *(const ushort4*)&hs2[(size_t)o1 + p4];
            ushort4 u2 = *(const ushort4*)&hs2[(size_t)o2 + p4];
            ushort4 u3 = *(const ushort4*)&hs2[(size_t)o3 + p4];
            acc.x += (bf2f(u0.x) + bf2f(u1.x)) + (bf2f(u2.x) + bf2f(u3.x));
            acc.y += (bf2f(u0.y) + bf2f(u1.y)) + (bf2f(u2.y) + bf2f(u3.y));
            acc.z += (bf2f(u0.z) + bf2f(u1.z)) + (bf2f(u2.z) + bf2f(u3.z));
            acc.w += (bf2f(u0.w) + bf2f(u1.w)) + (bf2f(u2.w) + bf2f(u3.w));
        }
        for (; e < m; e += 4) {
            int sl = e + grp;
            int o = __shfl(myoff, sl);
            if (sl < m) {
                ushort4 u = *(const ushort4*)&hs2[(size_t)o + p4];
                acc.x += bf2f(u.x); acc.y += bf2f(u.y);
                acc.z += bf2f(u.z); acc.w += bf2f(u.w);
            }
        }
    }
    acc.x += __shfl_xor(acc.x, 16); acc.y += __shfl_xor(acc.y, 16);
    acc.z += __shfl_xor(acc.z, 16); acc.w += __shfl_xor(acc.w, 16);
    acc.x += __shfl_xor(acc.x, 32); acc.y += __shfl_xor(acc.y, 32);
    acc.z += __shfl_xor(acc.z, 32); acc.w += __shfl_xor(acc.w, 32);
    if (grp == 0) {
        float dv = dinv[node];
        float vv[4] = {acc.x, acc.y, acc.z, acc.w};
#pragma unroll
        for (int j = 0; j < 4; j++) {
            int f = p4 + j;
            if (f < F2) out[(size_t)node * F2 + f] = vv[j] * dv + b2[f];
        }
    }
}

extern "C" void kernel_launch(void* const* d_in, const int* in_sizes, int n_in,
                              void* d_out, int out_size, void* d_ws, size_t ws_size,
                              hipStream_t stream) {
    const float* x  = (const float*)d_in[0];
    const int*   ei = (const int*)d_in[1];
    const float* W1 = (const float*)d_in[2];
    const float* b1 = (const float*)d_in[3];
    const float* W2 = (const float*)d_in[4];
    const float* b2 = (const float*)d_in[5];
    float* out = (float*)d_out;

    const int n = in_sizes[0] / FIN;   // 100000
    const int E = in_sizes[1] / 2;     // 1600000
    const int* src = ei;
    const int* dst = ei + E;
    const int nbuck   = (n + 255) >> BSH;              // 391 (<= NBMAX)
    const int nchunks = (E + CHUNK_P - 1) / CHUNK_P;   // 391
    const int nmm     = (n + MT - 1) / MT;             // 782
    const int nagg    = (n + 3) / 4;                   // 25000

    char* ws = (char*)d_ws;
    size_t off = 0;
    auto alloc = [&](size_t bytes) {
        void* p = ws + off;
        off = (off + bytes + 511) & ~(size_t)511;
        return p;
    };
    int*   gcur    = (int*)alloc((size_t)(NBMAX + 1) * 4);  // [NBMAX] = adj cursor
    int*   pairs   = (int*)alloc((size_t)nbuck * BCAP * 4); // ~9.6 MB
    int*   adj     = (int*)alloc((size_t)E * 4);
    int2*  rowinfo = (int2*)alloc((size_t)n * 8);
    float* dinv    = (float*)alloc((size_t)n * 4);
    unsigned short* hs1 = (unsigned short*)alloc((size_t)n * FP * 2);
    unsigned short* hs2 = (unsigned short*)alloc((size_t)n * FP * 2);
    unsigned short* h1b = (unsigned short*)alloc((size_t)n * FP * 2);

    k_zero<<<(NBMAX + 256) / 256, 256, 0, stream>>>(gcur, NBMAX + 1);
    k_part<<<nchunks, 256, 0, stream>>>(src, dst, gcur, pairs, E);
    k_build<<<nbuck, 256, 0, stream>>>(gcur, pairs, gcur + NBMAX, adj, rowinfo, dinv, n);
    k_mm1<<<nmm, 256, 0, stream>>>(x, W1, dinv, hs1, n);
    k_agg1<<<nagg, 256, 0, stream>>>(rowinfo, adj, hs1, dinv, b1, h1b, n, E);
    k_mm2<<<nmm, 256, 0, stream>>>(h1b, W2, dinv, hs2, n);
    k_agg2<<<nagg, 256, 0, stream>>>(rowinfo, adj, hs2, dinv, b2, out, n, E);
}

// Round 10
// 286.294 us; speedup vs baseline: 1.1735x; 1.1735x over previous
//
#include <hip/hip_runtime.h>

// GCN 2-layer forward. CSR-gather, bf16 payloads (stride-64, 128 B rows),
// 4-edges-per-gather aggregation with dinv[src] applied at gather time
// (hs1 is UNSCALED x@W1, so mm1 is independent of the CSR build and runs
// fused/concurrent with k_part in one dispatch).
// Pipeline (5 kernels): zero -> partmm1 (part-blocks ∥ mm1-blocks) ->
// build -> agg1 -> mm2 -> agg2.

#define FIN 128
#define F1  64
#define F2  41
#define FP  64     // payload row stride (bf16 elems): 128 B, 2 lines, aligned

#define BSH    8                 // bucket = dst >> 8 (256 nodes/bucket)
#define BCAP   6144              // per-bucket edge window (mean 4096, >30 sigma)
#define NBMAX  512               // max buckets (n <= 131072)
#define CHUNK_P 4096             // edges per part block (16/thread)

#define MT 128                   // GEMM M-tile
#define KC 16                    // GEMM K-chunk

__device__ __forceinline__ unsigned short f2bf(float f) {
    unsigned u = __builtin_bit_cast(unsigned, f);
    u += 0x7FFFu + ((u >> 16) & 1u);           // RNE
    return (unsigned short)(u >> 16);
}
__device__ __forceinline__ float bf2f(unsigned short h) {
    unsigned u = ((unsigned)h) << 16;
    return __builtin_bit_cast(float, u);
}

__global__ void k_zero(int* __restrict__ p, int n) {
    int i = blockIdx.x * blockDim.x + threadIdx.x;
    if (i < n) p[i] = 0;
}

// ---- fused: blocks [0,nchunks) = edge partition; rest = layer-1 GEMM -------
// part: chunk-local CSR in LDS, coalesced copy-out to bucket windows.
// mm1 : hs1 = bf16( x @ W1 )  (UNSCALED — dinv applied in agg1).
__global__ __launch_bounds__(256) void k_partmm1(
    const int* __restrict__ src, const int* __restrict__ dst,
    int* __restrict__ gcur, int* __restrict__ pairs, int E, int nchunks,
    const float* __restrict__ x, const float* __restrict__ W1,
    unsigned short* __restrict__ hs, int n) {
    __shared__ alignas(16) char smem[40960];
    int tid = threadIdx.x;
    if ((int)blockIdx.x < nchunks) {
        // ---------------- PART ----------------
        int* hist = (int*)smem;            // NBMAX
        int* gsh  = hist + NBMAX;          // NBMAX
        int* lex  = gsh + NBMAX;           // 256
        int* stot = lex + 256;             // 1
        int* limg = stot + 1;              // CHUNK_P
        int* lsh  = limg + CHUNK_P;        // CHUNK_P
        int e0  = blockIdx.x * CHUNK_P;
        int ds[CHUNK_P / 256], ss[CHUNK_P / 256];
#pragma unroll
        for (int j = 0; j < CHUNK_P / 256; j++) {
            int e = e0 + j * 256 + tid;
            if (e < E) { ds[j] = dst[e]; ss[j] = src[e]; } else ds[j] = -1;
        }
        hist[tid] = 0; hist[tid + 256] = 0;
        __syncthreads();
#pragma unroll
        for (int j = 0; j < CHUNK_P / 256; j++)
            if (ds[j] >= 0) atomicAdd(&hist[ds[j] >> BSH], 1);
        __syncthreads();
        int b0 = 2 * tid, b1 = 2 * tid + 1;
        int c0 = hist[b0], c1 = hist[b1];
        int s  = c0 + c1;
        lex[tid] = s;
        __syncthreads();
        for (int off = 1; off < 256; off <<= 1) {
            int v = lex[tid];
            int a = (tid >= off) ? lex[tid - off] : 0;
            __syncthreads();
            lex[tid] = v + a;
            __syncthreads();
        }
        int incl = lex[tid];
        if (tid == 255) stot[0] = incl;
        int ex = incl - s;
        int l0 = ex, l1 = ex + c0;
        int g0 = c0 ? atomicAdd(&gcur[b0], c0) : 0;
        int g1 = c1 ? atomicAdd(&gcur[b1], c1) : 0;
        hist[b0] = l0; hist[b1] = l1;
        gsh[b0]  = b0 * BCAP + g0 - l0;
        gsh[b1]  = b1 * BCAP + g1 - l1;
        __syncthreads();
#pragma unroll
        for (int j = 0; j < CHUNK_P / 256; j++) {
            if (ds[j] >= 0) {
                int b = ds[j] >> BSH;
                int p = atomicAdd(&hist[b], 1);
                limg[p] = (ss[j] << BSH) | (ds[j] & 255);
                lsh[p]  = gsh[b];
            }
        }
        __syncthreads();
        int tot = stot[0];
        for (int k = tid; k < tot; k += 256)
            pairs[k + lsh[k]] = limg[k];
    } else {
        // ---------------- MM1 ----------------
        float* Ws = (float*)smem;                        // FIN*F1 = 32 KB
        float (*As)[MT] = (float(*)[MT])(smem + FIN * F1 * 4);  // 8 KB
        int n0 = ((int)blockIdx.x - nchunks) * MT;
#pragma unroll
        for (int j = 0; j < 8; j++) {
            int f = j * 256 + tid;
            ((float4*)Ws)[f] = ((const float4*)W1)[f];
        }
        int m0 = (tid & 15) * 8;
        int c0 = (tid >> 4) * 4;
        int m_l = tid & 127;
        int kh  = (tid >> 7) * 8;
        bool mvalid = (n0 + m_l) < n;
        const float* xrow = x + (size_t)(n0 + m_l) * FIN + kh;
        float acc[8][4] = {};
        for (int kc = 0; kc < FIN; kc += KC) {
            __syncthreads();
            float4 v0 = mvalid ? *(const float4*)(xrow + kc)     : float4{0.f,0.f,0.f,0.f};
            float4 v1 = mvalid ? *(const float4*)(xrow + kc + 4) : float4{0.f,0.f,0.f,0.f};
            As[kh + 0][m_l] = v0.x; As[kh + 1][m_l] = v0.y;
            As[kh + 2][m_l] = v0.z; As[kh + 3][m_l] = v0.w;
            As[kh + 4][m_l] = v1.x; As[kh + 5][m_l] = v1.y;
            As[kh + 6][m_l] = v1.z; As[kh + 7][m_l] = v1.w;
            __syncthreads();
#pragma unroll
            for (int k = 0; k < KC; k++) {
                float4 a0 = *(const float4*)&As[k][m0];
                float4 a1 = *(const float4*)&As[k][m0 + 4];
                float4 w  = *(const float4*)&Ws[(kc + k) * F1 + c0];
                float a[8] = {a0.x, a0.y, a0.z, a0.w, a1.x, a1.y, a1.z, a1.w};
#pragma unroll
                for (int i = 0; i < 8; i++) {
                    acc[i][0] += a[i] * w.x;
                    acc[i][1] += a[i] * w.y;
                    acc[i][2] += a[i] * w.z;
                    acc[i][3] += a[i] * w.w;
                }
            }
        }
#pragma unroll
        for (int i = 0; i < 8; i++) {
            int node = n0 + m0 + i;
            if (node < n) {
                ushort4 o = { f2bf(acc[i][0]), f2bf(acc[i][1]),
                              f2bf(acc[i][2]), f2bf(acc[i][3]) };
                *(ushort4*)&hs[((size_t)node << 6) + c0] = o;
            }
        }
    }
}

// ---- pass 2: per-bucket CSR build in LDS, atomic adj-segment claim ---------
__global__ __launch_bounds__(256) void k_build(
    const int* __restrict__ gcur, const int* __restrict__ pairs,
    int* __restrict__ adjcur, int* __restrict__ adj,
    int2* __restrict__ rowinfo, float* __restrict__ dinv, int n) {
    __shared__ int lcnt[256];
    __shared__ int lex[256];
    __shared__ int lcur[256];
    __shared__ int ladj[BCAP];
    __shared__ int sbase;
    int tid = threadIdx.x;
    int b   = blockIdx.x;
    int cntb  = gcur[b]; if (cntb > BCAP) cntb = BCAP;
    int node0 = b << BSH;
    const int* pb = pairs + (size_t)b * BCAP;

    if (tid == 0) sbase = atomicAdd(adjcur, cntb);
    lcnt[tid] = 0;
    __syncthreads();
    for (int k = tid; k < cntb; k += 256) atomicAdd(&lcnt[pb[k] & 255], 1);
    __syncthreads();
    int own = lcnt[tid];
    lex[tid] = own;
    __syncthreads();
    for (int off = 1; off < 256; off <<= 1) {
        int val = lex[tid];
        int add = (tid >= off) ? lex[tid - off] : 0;
        __syncthreads();
        lex[tid] = val + add;
        __syncthreads();
    }
    int excl = lex[tid] - own;
    __syncthreads();
    lex[tid]  = excl;
    lcur[tid] = excl;
    __syncthreads();
    for (int k = tid; k < cntb; k += 256) {
        int pk  = pb[k];
        int pos = atomicAdd(&lcur[pk & 255], 1);
        ladj[pos] = pk >> BSH;
    }
    __syncthreads();
    int base = sbase;
    for (int k = tid; k < cntb; k += 256) adj[base + k] = ladj[k];
    int node = node0 + tid;
    if (node < n) {
        rowinfo[node] = make_int2(base + excl, own);
        dinv[node]    = rsqrtf((float)own + 1.0f);
    }
}

// ---- layer 1 aggregate: h1 = bf16(relu(dinv_d*(Σ dinv_s*hs[s] + dinv_d*hs[d]) + b1))
// hs is UNSCALED; dinv[src] batch-loaded coalesced alongside adj, shuffled
// with the offset, applied as FMA at gather time.
__global__ __launch_bounds__(256) void k_agg1(
    const int2* __restrict__ rowinfo, const int* __restrict__ adj,
    const unsigned short* __restrict__ hs, const float* __restrict__ dinv,
    const float* __restrict__ b1, unsigned short* __restrict__ h1b, int n, int E) {
    int node = blockIdx.x * 4 + (threadIdx.x >> 6);
    if (node >= n) return;
    int lane = threadIdx.x & 63;
    int grp  = lane >> 4;
    int p4   = (lane & 15) * 4;      // feature quad base
    int2 ri = rowinfo[node];
    int beg = ri.x, deg = ri.y;
    float dvn = dinv[node];
    float4 acc = {0.f, 0.f, 0.f, 0.f};
    if (grp == 0) {                  // self-loop: dinv[node]*hs[node]
        ushort4 u = *(const ushort4*)&hs[((size_t)node << 6) + p4];
        acc.x = dvn * bf2f(u.x); acc.y = dvn * bf2f(u.y);
        acc.z = dvn * bf2f(u.z); acc.w = dvn * bf2f(u.w);
    }
    for (int base = 0; base < deg; base += 64) {
        int m = deg - base; if (m > 64) m = 64;
        int idx = beg + base + lane;
        int sidx  = adj[idx < E ? idx : 0];
        float mydv = dinv[sidx];                 // coalesced-ish batch load
        int myoff  = sidx << 6;
        int e = 0;
        for (; e + 16 <= m; e += 16) {
            int o0 = __shfl(myoff, e + grp),      o1 = __shfl(myoff, e + 4 + grp);
            int o2 = __shfl(myoff, e + 8 + grp),  o3 = __shfl(myoff, e + 12 + grp);
            float d0 = __shfl(mydv, e + grp),     d1 = __shfl(mydv, e + 4 + grp);
            float d2 = __shfl(mydv, e + 8 + grp), d3 = __shfl(mydv, e + 12 + grp);
            ushort4 u0 = *(const ushort4*)&hs[(size_t)o0 + p4];
            ushort4 u1 = *(const ushort4*)&hs[(size_t)o1 + p4];
            ushort4 u2 = *(const ushort4*)&hs[(size_t)o2 + p4];
            ushort4 u3 = *(const ushort4*)&hs[(size_t)o3 + p4];
            acc.x += d0*bf2f(u0.x) + d1*bf2f(u1.x) + d2*bf2f(u2.x) + d3*bf2f(u3.x);
            acc.y += d0*bf2f(u0.y) + d1*bf2f(u1.y) + d2*bf2f(u2.y) + d3*bf2f(u3.y);
            acc.z += d0*bf2f(u0.z) + d1*bf2f(u1.z) + d2*bf2f(u2.z) + d3*bf2f(u3.z);
            acc.w += d0*bf2f(u0.w) + d1*bf2f(u1.w) + d2*bf2f(u2.w) + d3*bf2f(u3.w);
        }
        for (; e < m; e += 4) {
            int sl = e + grp;
            int o = __shfl(myoff, sl);
            float d = __shfl(mydv, sl);
            if (sl < m) {
                ushort4 u = *(const ushort4*)&hs[(size_t)o + p4];
                acc.x += d * bf2f(u.x); acc.y += d * bf2f(u.y);
                acc.z += d * bf2f(u.z); acc.w += d * bf2f(u.w);
            }
        }
    }
    acc.x += __shfl_xor(acc.x, 16); acc.y += __shfl_xor(acc.y, 16);
    acc.z += __shfl_xor(acc.z, 16); acc.w += __shfl_xor(acc.w, 16);
    acc.x += __shfl_xor(acc.x, 32); acc.y += __shfl_xor(acc.y, 32);
    acc.z += __shfl_xor(acc.z, 32); acc.w += __shfl_xor(acc.w, 32);
    if (grp == 0) {
        float4 bg = *(const float4*)&b1[p4];
        float vx = acc.x * dvn + bg.x; vx = vx > 0.f ? vx : 0.f;
        float vy = acc.y * dvn + bg.y; vy = vy > 0.f ? vy : 0.f;
        float vz = acc.z * dvn + bg.z; vz = vz > 0.f ? vz : 0.f;
        float vw = acc.w * dvn + bg.w; vw = vw > 0.f ? vw : 0.f;
        ushort4 o = { f2bf(vx), f2bf(vy), f2bf(vz), f2bf(vw) };
        *(ushort4*)&h1b[((size_t)node << 6) + p4] = o;
    }
}

// ---- layer 2 GEMM (tiled): hs2 = bf16( (h1 @ W2) * dinv ), stride 64 -------
__global__ __launch_bounds__(256) void k_mm2(
    const unsigned short* __restrict__ h1b, const float* __restrict__ W2,
    const float* __restrict__ dinv, unsigned short* __restrict__ hs2, int n) {
    __shared__ float Ws[F1 * FP];    // 16 KB padded (cols 41..63 = 0)
    __shared__ float As[KC][MT];
    int t  = threadIdx.x;
    int n0 = blockIdx.x * MT;
    for (int idx = t; idx < F1 * FP; idx += 256) {
        int k = idx >> 6, c = idx & 63;
        Ws[idx] = (c < F2) ? W2[k * F2 + c] : 0.f;
    }
    int m0 = (t & 15) * 8;
    int c0 = (t >> 4) * 4;
    int m_l = t & 127;
    int kh  = (t >> 7) * 8;
    bool mvalid = (n0 + m_l) < n;
    const unsigned short* hrow = h1b + ((size_t)(n0 + m_l) << 6) + kh;
    float acc[8][4] = {};
    for (int kc = 0; kc < F1; kc += KC) {
        __syncthreads();
        ushort4 u0 = mvalid ? *(const ushort4*)(hrow + kc)     : ushort4{0,0,0,0};
        ushort4 u1 = mvalid ? *(const ushort4*)(hrow + kc + 4) : ushort4{0,0,0,0};
        As[kh + 0][m_l] = bf2f(u0.x); As[kh + 1][m_l] = bf2f(u0.y);
        As[kh + 2][m_l] = bf2f(u0.z); As[kh + 3][m_l] = bf2f(u0.w);
        As[kh + 4][m_l] = bf2f(u1.x); As[kh + 5][m_l] = bf2f(u1.y);
        As[kh + 6][m_l] = bf2f(u1.z); As[kh + 7][m_l] = bf2f(u1.w);
        __syncthreads();
#pragma unroll
        for (int k = 0; k < KC; k++) {
            float4 a0 = *(const float4*)&As[k][m0];
            float4 a1 = *(const float4*)&As[k][m0 + 4];
            float4 w  = *(const float4*)&Ws[(kc + k) * FP + c0];
            float a[8] = {a0.x, a0.y, a0.z, a0.w, a1.x, a1.y, a1.z, a1.w};
#pragma unroll
            for (int i = 0; i < 8; i++) {
                acc[i][0] += a[i] * w.x;
                acc[i][1] += a[i] * w.y;
                acc[i][2] += a[i] * w.z;
                acc[i][3] += a[i] * w.w;
            }
        }
    }
#pragma unroll
    for (int i = 0; i < 8; i++) {
        int node = n0 + m0 + i;
        if (node < n) {
            float dv = dinv[node];
            ushort4 o = { f2bf(acc[i][0] * dv), f2bf(acc[i][1] * dv),
                          f2bf(acc[i][2] * dv), f2bf(acc[i][3] * dv) };
            *(ushort4*)&hs2[((size_t)node << 6) + c0] = o;
        }
    }
}

// ---- layer 2 aggregate: out = dinv*(gather+self) + b2 ----------------------
__global__ __launch_bounds__(256) void k_agg2(
    const int2* __restrict__ rowinfo, const int* __restrict__ adj,
    const unsigned short* __restrict__ hs2, const float* __restrict__ dinv,
    const float* __restrict__ b2, float* __restrict__ out, int n, int E) {
    int node = blockIdx.x * 4 + (threadIdx.x >> 6);
    if (node >= n) return;
    int lane = threadIdx.x & 63;
    int grp  = lane >> 4;
    int p4   = (lane & 15) * 4;
    int2 ri = rowinfo[node];
    int beg = ri.x, deg = ri.y;
    float4 acc = {0.f, 0.f, 0.f, 0.f};
    if (grp == 0) {
        ushort4 u = *(const ushort4*)&hs2[((size_t)node << 6) + p4];
        acc.x = bf2f(u.x); acc.y = bf2f(u.y); acc.z = bf2f(u.z); acc.w = bf2f(u.w);
    }
    for (int base = 0; base < deg; base += 64) {
        int m = deg - base; if (m > 64) m = 64;
        int idx = beg + base + lane;
        int myoff = adj[idx < E ? idx : 0] << 6;
        int e = 0;
        for (; e + 16 <= m; e += 16) {
            int o0 = __shfl(myoff, e + grp),      o1 = __shfl(myoff, e + 4 + grp);
            int o2 = __shfl(myoff, e + 8 + grp),  o3 = __shfl(myoff, e + 12 + grp);
            ushort4 u0 = *(const ushort4*)&hs2[(size_t)o0 + p4];
            ushort4 u1 = *(const ushort4*)&hs2[(size_t)o1 + p4];
            ushort4 u2 = *(const ushort4*)&hs2[(size_t)o2 + p4];
            ushort4 u3 = *(const ushort4*)&hs2[(size_t)o3 + p4];
            acc.x += (bf2f(u0.x) + bf2f(u1.x)) + (bf2f(u2.x) + bf2f(u3.x));
            acc.y += (bf2f(u0.y) + bf2f(u1.y)) + (bf2f(u2.y) + bf2f(u3.y));
            acc.z += (bf2f(u0.z) + bf2f(u1.z)) + (bf2f(u2.z) + bf2f(u3.z));
            acc.w += (bf2f(u0.w) + bf2f(u1.w)) + (bf2f(u2.w) + bf2f(u3.w));
        }
        for (; e < m; e += 4) {
            int sl = e + grp;
            int o = __shfl(myoff, sl);
            if (sl < m) {
                ushort4 u = *(const ushort4*)&hs2[(size_t)o + p4];
                acc.x += bf2f(u.x); acc.y += bf2f(u.y);
                acc.z += bf2f(u.z); acc.w += bf2f(u.w);
            }
        }
    }
    acc.x += __shfl_xor(acc.x, 16); acc.y += __shfl_xor(acc.y, 16);
    acc.z += __shfl_xor(acc.z, 16); acc.w += __shfl_xor(acc.w, 16);
    acc.x += __shfl_xor(acc.x, 32); acc.y += __shfl_xor(acc.y, 32);
    acc.z += __shfl_xor(acc.z, 32); acc.w += __shfl_xor(acc.w, 32);
    if (grp == 0) {
        float dv = dinv[node];
        float vv[4] = {acc.x, acc.y, acc.z, acc.w};
#pragma unroll
        for (int j = 0; j < 4; j++) {
            int f = p4 + j;
            if (f < F2) out[(size_t)node * F2 + f] = vv[j] * dv + b2[f];
        }
    }
}

extern "C" void kernel_launch(void* const* d_in, const int* in_sizes, int n_in,
                              void* d_out, int out_size, void* d_ws, size_t ws_size,
                              hipStream_t stream) {
    const float* x  = (const float*)d_in[0];
    const int*   ei = (const int*)d_in[1];
    const float* W1 = (const float*)d_in[2];
    const float* b1 = (const float*)d_in[3];
    const float* W2 = (const float*)d_in[4];
    const float* b2 = (const float*)d_in[5];
    float* out = (float*)d_out;

    const int n = in_sizes[0] / FIN;   // 100000
    const int E = in_sizes[1] / 2;     // 1600000
    const int* src = ei;
    const int* dst = ei + E;
    const int nbuck   = (n + 255) >> BSH;              // 391 (<= NBMAX)
    const int nchunks = (E + CHUNK_P - 1) / CHUNK_P;   // 391
    const int nmm     = (n + MT - 1) / MT;             // 782
    const int nagg    = (n + 3) / 4;                   // 25000

    char* ws = (char*)d_ws;
    size_t off = 0;
    auto alloc = [&](size_t bytes) {
        void* p = ws + off;
        off = (off + bytes + 511) & ~(size_t)511;
        return p;
    };
    int*   gcur    = (int*)alloc((size_t)(NBMAX + 1) * 4);  // [NBMAX] = adj cursor
    int*   pairs   = (int*)alloc((size_t)nbuck * BCAP * 4); // ~9.6 MB
    int*   adj     = (int*)alloc((size_t)E * 4);
    int2*  rowinfo = (int2*)alloc((size_t)n * 8);
    float* dinv    = (float*)alloc((size_t)n * 4);
    unsigned short* hs1 = (unsigned short*)alloc((size_t)n * FP * 2);
    unsigned short* hs2 = (unsigned short*)alloc((size_t)n * FP * 2);
    unsigned short* h1b = (unsigned short*)alloc((size_t)n * FP * 2);

    k_zero<<<(NBMAX + 256) / 256, 256, 0, stream>>>(gcur, NBMAX + 1);
    k_partmm1<<<nchunks + nmm, 256, 0, stream>>>(src, dst, gcur, pairs, E, nchunks,
                                                 x, W1, hs1, n);
    k_build<<<nbuck, 256, 0, stream>>>(gcur, pairs, gcur + NBMAX, adj, rowinfo, dinv, n);
    k_agg1<<<nagg, 256, 0, stream>>>(rowinfo, adj, hs1, dinv, b1, h1b, n, E);
    k_mm2<<<nmm, 256, 0, stream>>>(h1b, W2, dinv, hs2, n);
    k_agg2<<<nagg, 256, 0, stream>>>(rowinfo, adj, hs2, dinv, b2, out, n, E);
}